// Round 8
// baseline (479.526 us; speedup 1.0000x reference)
//
#include <hip/hip_runtime.h>

#define NN   100000
#define NE   500000
#define DD   128
#define HH   4
#define HIDD 512
#define EPSF 1e-5f

typedef __bf16 bf16x8 __attribute__((ext_vector_type(8)));
typedef float  f32x4  __attribute__((ext_vector_type(4)));
typedef unsigned short u16x8 __attribute__((ext_vector_type(8)));

__device__ __forceinline__ unsigned short f2b(float f) {
  unsigned u = __float_as_uint(f);
  unsigned r = (u + 0x7FFFu + ((u >> 16) & 1)) >> 16;
  return (unsigned short)r;
}
__device__ __forceinline__ float b2f(unsigned short s) {
  return __uint_as_float(((unsigned)s) << 16);
}

// all weight casts + bias pack in ONE launch (209 blocks)
__global__ void k_castw(const float* __restrict__ Wq, const float* __restrict__ Wk,
                        const float* __restrict__ Wv, const float* __restrict__ Wsk,
                        const float* __restrict__ Wo, const float* __restrict__ W1,
                        const float* __restrict__ W2,
                        const float* __restrict__ bq, const float* __restrict__ bk,
                        const float* __restrict__ bv, const float* __restrict__ bs,
                        unsigned short* __restrict__ Wqkvs, unsigned short* __restrict__ Wob,
                        unsigned short* __restrict__ W1b, unsigned short* __restrict__ W2b,
                        float* __restrict__ bias512) {
  int i = blockIdx.x * 256 + threadIdx.x;
  if (i < 53248) {
    int e = i * 4;
    const float* src; unsigned short* dst; int off;
    if (e < 65536) {
      int seg = e >> 14;
      const float* s4[4] = {Wq, Wk, Wv, Wsk};
      src = s4[seg]; dst = Wqkvs + (seg << 14); off = e & 16383;
    } else if (e < 81920) { src = Wo;  dst = Wob; off = e - 65536; }
    else if (e < 147456)  { src = W1;  dst = W1b; off = e - 81920; }
    else                  { src = W2;  dst = W2b; off = e - 147456; }
    float4 v = *(const float4*)&src[off];
    ushort4 o; o.x = f2b(v.x); o.y = f2b(v.y); o.z = f2b(v.z); o.w = f2b(v.w);
    *(ushort4*)&dst[off] = o;
  } else if (i < 53376) {
    int b4 = (i - 53248) * 4;
    const float* srcs[4] = {bq, bk, bv, bs};
#pragma unroll
    for (int j = 0; j < 4; j++) {
      int idx = b4 + j;
      bias512[idx] = srcs[idx >> 7][idx & 127];
    }
  }
}

// ---------------- CSR build ----------------
__global__ void k_zero_cnt(int* __restrict__ cnt) {
  int i = blockIdx.x * 256 + threadIdx.x;
  if (i < NN) cnt[i] = 0;
}
__global__ void k_count(const int* __restrict__ ei, int* __restrict__ cnt) {
  int e = blockIdx.x * 256 + threadIdx.x;
  if (e < NE) atomicAdd(&cnt[ei[NE + e]], 1);
}
__global__ void k_scan1(const int* __restrict__ cnt, int* __restrict__ rowptr, int* __restrict__ part) {
  __shared__ int sh[256];
  int i = blockIdx.x * 256 + threadIdx.x;
  int v = (i < NN) ? cnt[i] : 0;
  sh[threadIdx.x] = v; __syncthreads();
  for (int off = 1; off < 256; off <<= 1) {
    int t = (threadIdx.x >= off) ? sh[threadIdx.x - off] : 0;
    __syncthreads();
    sh[threadIdx.x] += t;
    __syncthreads();
  }
  if (i < NN) rowptr[i] = sh[threadIdx.x] - v;  // exclusive
  if (threadIdx.x == 255) part[blockIdx.x] = sh[255];
}
__global__ void k_scan2(const int* __restrict__ part, int* __restrict__ partx) {
  __shared__ int sh[512];
  int t = threadIdx.x;
  int v = (t < 391) ? part[t] : 0;
  sh[t] = v; __syncthreads();
  for (int off = 1; off < 512; off <<= 1) {
    int u = (t >= off) ? sh[t - off] : 0;
    __syncthreads();
    sh[t] += u;
    __syncthreads();
  }
  partx[t] = sh[t] - v;
}
__global__ void k_scan3(int* __restrict__ rowptr, const int* __restrict__ partx, int* __restrict__ cnt) {
  int i = blockIdx.x * 256 + threadIdx.x;
  if (i < NN) {
    int r = rowptr[i] + partx[i >> 8];
    rowptr[i] = r;
    cnt[i] = r;
  }
  if (i == 0) rowptr[NN] = NE;
}
__global__ void k_scatter(const int* __restrict__ ei, int* __restrict__ cnt, int* __restrict__ csr_src) {
  int e = blockIdx.x * 256 + threadIdx.x;
  if (e >= NE) return;
  int d = ei[NE + e];
  int pos = atomicAdd(&cnt[d], 1);
  csr_src[pos] = ei[e];
}

// ---------------- register-resident GEMM (no LDS, no barriers) ----------------
// Wave = 32 rows x 128 cols; block = 4 waves = 128 rows. W frags held in VGPRs.
// MODE 0: out bf16 at ldo=512, col0 = blockIdx.y*128 (qkvs / FFN1)
// MODE 1: + residual resF (fp32, ld DD) + LayerNorm -> outB bf16 ldo=DD (out-proj+LN1)
// MODE 2: + residual resB (bf16, ld DD) + LayerNorm -> outF fp32 ldo=DD (FFN2+LN2)
template <int KTOT, int LDA, bool F32A, bool RELU, int MODE>
__global__ __launch_bounds__(256, 2) void k_gemm_reg(const void* __restrict__ Av,
                                                     const unsigned short* __restrict__ W,
                                                     const float* __restrict__ bias,
                                                     const float* __restrict__ resF,
                                                     const unsigned short* __restrict__ resB,
                                                     const float* __restrict__ lw,
                                                     const float* __restrict__ lb,
                                                     float* __restrict__ outF,
                                                     unsigned short* __restrict__ outB) {
  const int t = threadIdx.x;
  const int w = t >> 6, l = t & 63;
  const int n0 = blockIdx.x * 128 + w * 32;  // this wave's first row
  const int col0 = (MODE == 0) ? blockIdx.y * 128 : 0;
  const int lq = l & 15, hq = l >> 4;

  f32x4 acc[2][8] = {};
#pragma unroll 1
  for (int kb = 0; kb < KTOT; kb += 128) {
    // B fragments for this K-chunk: full 128 cols x 128 k, in registers
    bf16x8 bfr[4][8];
#pragma unroll
    for (int ks = 0; ks < 4; ks++)
#pragma unroll
      for (int ct = 0; ct < 8; ct++)
        bfr[ks][ct] = *(const bf16x8*)&W[(size_t)(col0 + ct * 16 + lq) * KTOT + kb + ks * 32 + hq * 8];
#pragma unroll
    for (int ks = 0; ks < 4; ks++) {
      bf16x8 a[2];
#pragma unroll
      for (int rt = 0; rt < 2; rt++) {
        const int row = n0 + rt * 16 + lq;
        if constexpr (F32A) {
          const float* A = (const float*)Av;
          float4 f0 = make_float4(0.f, 0.f, 0.f, 0.f), f1 = f0;
          if (row < NN) {
            const float* p = A + (size_t)row * LDA + kb + ks * 32 + hq * 8;
            f0 = *(const float4*)p;
            f1 = *(const float4*)(p + 4);
          }
          u16x8 tmp;
          tmp[0] = f2b(f0.x); tmp[1] = f2b(f0.y); tmp[2] = f2b(f0.z); tmp[3] = f2b(f0.w);
          tmp[4] = f2b(f1.x); tmp[5] = f2b(f1.y); tmp[6] = f2b(f1.z); tmp[7] = f2b(f1.w);
          a[rt] = *(bf16x8*)&tmp;
        } else {
          bf16x8 z = {};
          a[rt] = (row < NN)
              ? *(const bf16x8*)&((const unsigned short*)Av)[(size_t)row * LDA + kb + ks * 32 + hq * 8]
              : z;
        }
      }
#pragma unroll
      for (int rt = 0; rt < 2; rt++)
#pragma unroll
        for (int ct = 0; ct < 8; ct++)
          acc[rt][ct] = __builtin_amdgcn_mfma_f32_16x16x32_bf16(a[rt], bfr[ks][ct], acc[rt][ct], 0, 0, 0);
    }
  }

  if constexpr (MODE == 0) {
#pragma unroll
    for (int rt = 0; rt < 2; rt++) {
      const int rbase = n0 + rt * 16 + hq * 4;
#pragma unroll
      for (int ct = 0; ct < 8; ct++) {
        const int col = col0 + ct * 16 + lq;
        const float bs = bias[col];
#pragma unroll
        for (int j = 0; j < 4; j++) {
          const int r = rbase + j;
          if (r < NN) {
            float vv = acc[rt][ct][j] + bs;
            if (RELU) vv = fmaxf(vv, 0.f);
            outB[(size_t)r * 512 + col] = f2b(vv);
          }
        }
      }
    }
  } else {
    // bias + residual
#pragma unroll
    for (int rt = 0; rt < 2; rt++) {
      const int rbase = n0 + rt * 16 + hq * 4;
#pragma unroll
      for (int ct = 0; ct < 8; ct++) {
        const int col = ct * 16 + lq;
        const float bs = bias[col];
#pragma unroll
        for (int j = 0; j < 4; j++) {
          const int r = rbase + j;
          float rv = 0.f;
          if (r < NN)
            rv = (MODE == 1) ? resF[(size_t)r * DD + col] : b2f(resB[(size_t)r * DD + col]);
          acc[rt][ct][j] += bs + rv;
        }
      }
    }
    // per-row LayerNorm: row's 128 cols = 8 ct regs x 16 lanes (same hq group)
#pragma unroll
    for (int rt = 0; rt < 2; rt++) {
      const int rbase = n0 + rt * 16 + hq * 4;
#pragma unroll
      for (int j = 0; j < 4; j++) {
        float s = 0.f;
#pragma unroll
        for (int ct = 0; ct < 8; ct++) s += acc[rt][ct][j];
        s += __shfl_xor(s, 1, 64); s += __shfl_xor(s, 2, 64);
        s += __shfl_xor(s, 4, 64); s += __shfl_xor(s, 8, 64);
        const float mu = s * (1.f / 128.f);
        float vs = 0.f;
#pragma unroll
        for (int ct = 0; ct < 8; ct++) { float d = acc[rt][ct][j] - mu; vs += d * d; }
        vs += __shfl_xor(vs, 1, 64); vs += __shfl_xor(vs, 2, 64);
        vs += __shfl_xor(vs, 4, 64); vs += __shfl_xor(vs, 8, 64);
        const float rs = rsqrtf(vs * (1.f / 128.f) + EPSF);
        const int r = rbase + j;
        if (r < NN) {
#pragma unroll
          for (int ct = 0; ct < 8; ct++) {
            const int col = ct * 16 + lq;
            float yv = (acc[rt][ct][j] - mu) * rs * lw[col] + lb[col];
            if (MODE == 2) outF[(size_t)r * DD + col] = yv;
            else           outB[(size_t)r * DD + col] = f2b(yv);
          }
        }
      }
    }
  }
}

// ---------------- single-pass fused attention ----------------
// qkvsb [N,512] bf16: q 0:128, k 128:256, v 256:384, skip 384:512 (conv written in-place).
__global__ __launch_bounds__(256) void k_attn(const int* __restrict__ csr_src,
                                              const int* __restrict__ rowptr,
                                              unsigned short* qkvsb) {
  const int l = threadIdx.x & 31;
  const int node = blockIdx.x * 8 + (threadIdx.x >> 5);  // grid exact: 12500*8
  const int row0 = rowptr[node], row1 = rowptr[node + 1];
  ushort4 qu = *(const ushort4*)&qkvsb[(size_t)node * 512 + l * 4];
  const float qx = b2f(qu.x), qy = b2f(qu.y), qz = b2f(qu.z), qw = b2f(qu.w);
  float ax = 0.f, ay = 0.f, az = 0.f, aw = 0.f, z = 0.f;
  for (int p = row0; p < row1; ++p) {
    int s = csr_src[p];
    const unsigned short* base = &qkvsb[(size_t)s * 512];
    ushort4 kr = *(const ushort4*)(base + 128 + l * 4);  // k row
    ushort4 vr = *(const ushort4*)(base + 256 + l * 4);  // v row
    float d = qx * b2f(kr.x) + qy * b2f(kr.y) + qz * b2f(kr.z) + qw * b2f(kr.w);
    d += __shfl_xor(d, 1, 32);
    d += __shfl_xor(d, 2, 32);
    d += __shfl_xor(d, 4, 32);
    float e = __expf(d * 0.17677669529663687f);  // 1/sqrt(32)
    z += e;
    ax += e * b2f(vr.x); ay += e * b2f(vr.y);
    az += e * b2f(vr.z); aw += e * b2f(vr.w);
  }
  const float rz = (z > 0.f) ? (1.f / z) : 0.f;  // guard in-degree-0 nodes
  ushort4 su = *(const ushort4*)&qkvsb[(size_t)node * 512 + 384 + l * 4];
  ushort4 o;
  o.x = f2b(b2f(su.x) + ax * rz);
  o.y = f2b(b2f(su.y) + ay * rz);
  o.z = f2b(b2f(su.z) + az * rz);
  o.w = f2b(b2f(su.w) + aw * rz);
  *(ushort4*)&qkvsb[(size_t)node * 512 + 384 + l * 4] = o;
}

extern "C" void kernel_launch(void* const* d_in, const int* in_sizes, int n_in,
                              void* d_out, int out_size, void* d_ws, size_t ws_size,
                              hipStream_t stream) {
  const float* x   = (const float*)d_in[0];
  const int*   ei  = (const int*)d_in[1];
  const float* Wq  = (const float*)d_in[2];
  const float* bq  = (const float*)d_in[3];
  const float* Wk  = (const float*)d_in[4];
  const float* bk  = (const float*)d_in[5];
  const float* Wv  = (const float*)d_in[6];
  const float* bv  = (const float*)d_in[7];
  const float* Wsk = (const float*)d_in[8];
  const float* bsk = (const float*)d_in[9];
  const float* Wo  = (const float*)d_in[10];
  const float* bo  = (const float*)d_in[11];
  const float* l1w = (const float*)d_in[12];
  const float* l1b = (const float*)d_in[13];
  const float* l2w = (const float*)d_in[14];
  const float* l2b = (const float*)d_in[15];
  const float* W1  = (const float*)d_in[16];
  const float* b1  = (const float*)d_in[17];
  const float* W2  = (const float*)d_in[18];
  const float* b2  = (const float*)d_in[19];

  // ---- workspace layout (~132 MB peak) ----
  unsigned short* wsu = (unsigned short*)d_ws;
  unsigned short* qkvsb = wsu;                           // [N,512] bf16 (later: hid)
  unsigned short* out2b = wsu + (size_t)NN * 512;        // [N,128] bf16
  int* csr_src = (int*)(out2b + (size_t)NN * DD);        // NE
  int* rowptr  = csr_src + NE;                           // N+1
  int* cnt     = rowptr + NN + 1;                        // N
  int* part    = cnt + NN;                               // 391
  int* partx   = part + 512;                             // 512
  size_t woff = (size_t)((partx + 512) - (int*)d_ws);
  woff = (woff + 3) & ~(size_t)3;                        // 16B-align weights
  unsigned short* Wqkvs = (unsigned short*)((int*)d_ws + woff);  // [512,128]
  unsigned short* Wob   = Wqkvs + 512 * DD;                      // [128,128]
  unsigned short* W1b   = Wob + DD * DD;                         // [512,128]
  unsigned short* W2b   = W1b + (size_t)HIDD * DD;               // [128,512]
  float* bias512        = (float*)(W2b + (size_t)DD * HIDD);

  unsigned short* hid = qkvsb;  // qkvsb dead after out-proj
  float* outf = (float*)d_out;

  const int GX = (NN + 127) / 128;  // 782
  dim3 blk(256);

  // weights/biases cast+pack (one launch)
  k_castw<<<dim3(209), blk, 0, stream>>>(Wq, Wk, Wv, Wsk, Wo, W1, W2, bq, bk, bv, bsk,
                                         Wqkvs, Wob, W1b, W2b, bias512);

  // CSR build
  k_zero_cnt<<<dim3(391), blk, 0, stream>>>(cnt);
  k_count<<<dim3(1954), blk, 0, stream>>>(ei, cnt);
  k_scan1<<<dim3(391), blk, 0, stream>>>(cnt, rowptr, part);
  k_scan2<<<dim3(1), dim3(512), 0, stream>>>(part, partx);
  k_scan3<<<dim3(391), blk, 0, stream>>>(rowptr, partx, cnt);
  k_scatter<<<dim3(1954), blk, 0, stream>>>(ei, cnt, csr_src);

  // fused q|k|v|skip projection: x fp32 -> qkvsb bf16 [N,512]
  k_gemm_reg<128, 128, true, false, 0><<<dim3(GX, 4), blk, 0, stream>>>(
      x, Wqkvs, bias512, nullptr, nullptr, nullptr, nullptr, nullptr, qkvsb);

  // single-pass attention (conv lands in skip slot)
  k_attn<<<dim3(12500), blk, 0, stream>>>(csr_src, rowptr, qkvsb);

  // out projection (A = conv slot, lda=512) + residual(x fp32) + LN1 -> out2b bf16
  k_gemm_reg<128, 512, false, false, 1><<<dim3(GX), blk, 0, stream>>>(
      qkvsb + 384, Wob, bo, x, nullptr, l1w, l1b, nullptr, out2b);

  // FFN1 (relu) -> hid bf16 [N,512]
  k_gemm_reg<128, 128, false, true, 0><<<dim3(GX, 4), blk, 0, stream>>>(
      out2b, W1b, b1, nullptr, nullptr, nullptr, nullptr, nullptr, hid);

  // FFN2 (K=512) + residual(out2b bf16) + LN2 -> d_out fp32
  k_gemm_reg<512, 512, false, false, 2><<<dim3(GX), blk, 0, stream>>>(
      hid, W2b, b2, nullptr, out2b, l2w, l2b, outf, nullptr);
}

// Round 9
// 336.689 us; speedup vs baseline: 1.4242x; 1.4242x over previous
//
#include <hip/hip_runtime.h>

#define NN   100000
#define NE   500000
#define DD   128
#define HH   4
#define HIDD 512
#define EPSF 1e-5f

typedef __bf16 bf16x8 __attribute__((ext_vector_type(8)));
typedef float  f32x4  __attribute__((ext_vector_type(4)));

__device__ __forceinline__ unsigned short f2b(float f) {
  unsigned u = __float_as_uint(f);
  unsigned r = (u + 0x7FFFu + ((u >> 16) & 1)) >> 16;
  return (unsigned short)r;
}
__device__ __forceinline__ float b2f(unsigned short s) {
  return __uint_as_float(((unsigned)s) << 16);
}

// async global->LDS, 16B per lane; LDS dest is wave-uniform base (+lane*16 by HW)
#define GLOAD16(ldsp, gp) __builtin_amdgcn_global_load_lds(                      \
    (const __attribute__((address_space(1))) void*)(gp),                         \
    (__attribute__((address_space(3))) void*)(ldsp), 16, 0, 0)

// stage a 128x128 bf16 W tile: linear LDS dest, inverse-swizzled global source.
// read side uses slot (c16 ^ (row&7)).
__device__ __forceinline__ void stageW(unsigned short* lds, const unsigned short* g,
                                       int ldg, int t) {
  const int w = t >> 6, l = t & 63;
#pragma unroll
  for (int i = 0; i < 8; i++) {
    const int chunk0 = i * 256 + w * 64;   // wave-uniform
    const int chunk = chunk0 + l;
    const int row = chunk >> 4, c16 = chunk & 15;
    const int gslot = c16 ^ (row & 7);
    GLOAD16(lds + (size_t)chunk0 * 8, g + (size_t)row * ldg + gslot * 8);
  }
}

// fp32 -> bf16 cast (x -> xb)
__global__ void k_cast(const float* __restrict__ src, unsigned short* __restrict__ dst, int n) {
  int i = (blockIdx.x * 256 + threadIdx.x) * 4;
  if (i >= n) return;
  float4 v = *(const float4*)&src[i];
  ushort4 o;
  o.x = f2b(v.x); o.y = f2b(v.y); o.z = f2b(v.z); o.w = f2b(v.w);
  *(ushort4*)&dst[i] = o;
}

// all weight casts + bias pack in ONE launch (209 blocks)
__global__ void k_castw(const float* __restrict__ Wq, const float* __restrict__ Wk,
                        const float* __restrict__ Wv, const float* __restrict__ Wsk,
                        const float* __restrict__ Wo, const float* __restrict__ W1,
                        const float* __restrict__ W2,
                        const float* __restrict__ bq, const float* __restrict__ bk,
                        const float* __restrict__ bv, const float* __restrict__ bs,
                        unsigned short* __restrict__ Wqkvs, unsigned short* __restrict__ Wob,
                        unsigned short* __restrict__ W1b, unsigned short* __restrict__ W2b,
                        float* __restrict__ bias512) {
  int i = blockIdx.x * 256 + threadIdx.x;
  if (i < 53248) {
    int e = i * 4;
    const float* src; unsigned short* dst; int off;
    if (e < 65536) {
      int seg = e >> 14;
      const float* s4[4] = {Wq, Wk, Wv, Wsk};
      src = s4[seg]; dst = Wqkvs + (seg << 14); off = e & 16383;
    } else if (e < 81920) { src = Wo;  dst = Wob; off = e - 65536; }
    else if (e < 147456)  { src = W1;  dst = W1b; off = e - 81920; }
    else                  { src = W2;  dst = W2b; off = e - 147456; }
    float4 v = *(const float4*)&src[off];
    ushort4 o; o.x = f2b(v.x); o.y = f2b(v.y); o.z = f2b(v.z); o.w = f2b(v.w);
    *(ushort4*)&dst[off] = o;
  } else if (i < 53376) {
    int b4 = (i - 53248) * 4;
    const float* srcs[4] = {bq, bk, bv, bs};
#pragma unroll
    for (int j = 0; j < 4; j++) {
      int idx = b4 + j;
      bias512[idx] = srcs[idx >> 7][idx & 127];
    }
  }
}

// ---------------- CSR build ----------------
__global__ void k_zero_cnt(int* __restrict__ cnt) {
  int i = blockIdx.x * 256 + threadIdx.x;
  if (i < NN) cnt[i] = 0;
}
__global__ void k_count(const int* __restrict__ ei, int* __restrict__ cnt) {
  int e = blockIdx.x * 256 + threadIdx.x;
  if (e < NE) atomicAdd(&cnt[ei[NE + e]], 1);
}
__global__ void k_scan1(const int* __restrict__ cnt, int* __restrict__ rowptr, int* __restrict__ part) {
  __shared__ int sh[256];
  int i = blockIdx.x * 256 + threadIdx.x;
  int v = (i < NN) ? cnt[i] : 0;
  sh[threadIdx.x] = v; __syncthreads();
  for (int off = 1; off < 256; off <<= 1) {
    int t = (threadIdx.x >= off) ? sh[threadIdx.x - off] : 0;
    __syncthreads();
    sh[threadIdx.x] += t;
    __syncthreads();
  }
  if (i < NN) rowptr[i] = sh[threadIdx.x] - v;  // exclusive
  if (threadIdx.x == 255) part[blockIdx.x] = sh[255];
}
__global__ void k_scan2(const int* __restrict__ part, int* __restrict__ partx) {
  __shared__ int sh[512];
  int t = threadIdx.x;
  int v = (t < 391) ? part[t] : 0;
  sh[t] = v; __syncthreads();
  for (int off = 1; off < 512; off <<= 1) {
    int u = (t >= off) ? sh[t - off] : 0;
    __syncthreads();
    sh[t] += u;
    __syncthreads();
  }
  partx[t] = sh[t] - v;
}
__global__ void k_scan3(int* __restrict__ rowptr, const int* __restrict__ partx, int* __restrict__ cnt) {
  int i = blockIdx.x * 256 + threadIdx.x;
  if (i < NN) {
    int r = rowptr[i] + partx[i >> 8];
    rowptr[i] = r;
    cnt[i] = r;
  }
  if (i == 0) rowptr[NN] = NE;
}
__global__ void k_scatter(const int* __restrict__ ei, int* __restrict__ cnt, int* __restrict__ csr_src) {
  int e = blockIdx.x * 256 + threadIdx.x;
  if (e >= NE) return;
  int d = ei[NE + e];
  int pos = atomicAdd(&cnt[d], 1);
  csr_src[pos] = ei[e];
}

// ---------------- GEMM: W in LDS (32KB), A global->reg direct ----------------
// Block = 128 rows x 128 cols, 4 waves (each 32 rows).
// MODE 0: 1D grid GX*4; b>>2 = row-tile, b&3 = col-group; out bf16 ldo=512.
// MODE 1: grid GX; + residual resB (bf16) + LN -> outB bf16 ldo=DD
// MODE 2: grid GX; + residual resB (bf16) + LN -> outF fp32 ldo=DD
template <int KTOT, int LDA, bool RELU, int MODE>
__global__ __launch_bounds__(256, 3) void k_gemm_wl(const unsigned short* __restrict__ A,
                                                    const unsigned short* __restrict__ W,
                                                    const float* __restrict__ bias,
                                                    const unsigned short* __restrict__ resB,
                                                    const float* __restrict__ lw,
                                                    const float* __restrict__ lb,
                                                    float* __restrict__ outF,
                                                    unsigned short* __restrict__ outB) {
  __shared__ __align__(16) unsigned short Ws[128 * 128];
  const int t = threadIdx.x;
  const int w = t >> 6, l = t & 63;
  const int bx   = (MODE == 0) ? (blockIdx.x >> 2) : blockIdx.x;
  const int col0 = (MODE == 0) ? (blockIdx.x & 3) * 128 : 0;
  const int n0 = bx * 128 + w * 32;  // this wave's first row
  const int lq = l & 15, hq = l >> 4;

  f32x4 acc[2][8] = {};
#pragma unroll 1
  for (int kc = 0; kc < KTOT / 128; ++kc) {
    const int kb = kc * 128;
    // prefetch this chunk's A-fragments to registers (8 x dwordx4, predicated)
    bf16x8 afr[4][2];
#pragma unroll
    for (int ks = 0; ks < 4; ks++)
#pragma unroll
      for (int rt = 0; rt < 2; rt++) {
        const int row = n0 + rt * 16 + lq;
        bf16x8 zz = {};
        afr[ks][rt] = (row < NN)
            ? *(const bf16x8*)&A[(size_t)row * LDA + kb + ks * 32 + hq * 8]
            : zz;
      }
    if (kc > 0) __syncthreads();  // prior Ws readers done
    stageW(Ws, W + (size_t)col0 * KTOT + kb, KTOT, t);
    __syncthreads();              // W chunk ready (drains afr loads too)
#pragma unroll
    for (int ks = 0; ks < 4; ks++) {
      bf16x8 b[8];
      const int c16 = ks * 4 + hq;
#pragma unroll
      for (int ct = 0; ct < 8; ct++) {
        const int row = ct * 16 + lq;
        b[ct] = *(const bf16x8*)&Ws[row * 128 + ((c16 ^ (row & 7)) * 8)];
      }
#pragma unroll
      for (int rt = 0; rt < 2; rt++)
#pragma unroll
        for (int ct = 0; ct < 8; ct++)
          acc[rt][ct] = __builtin_amdgcn_mfma_f32_16x16x32_bf16(afr[ks][rt], b[ct], acc[rt][ct], 0, 0, 0);
    }
  }

  if constexpr (MODE == 0) {
#pragma unroll
    for (int rt = 0; rt < 2; rt++) {
      const int rbase = n0 + rt * 16 + hq * 4;
#pragma unroll
      for (int ct = 0; ct < 8; ct++) {
        const int col = col0 + ct * 16 + lq;
        const float bs = bias[col];
#pragma unroll
        for (int j = 0; j < 4; j++) {
          const int r = rbase + j;
          if (r < NN) {
            float vv = acc[rt][ct][j] + bs;
            if (RELU) vv = fmaxf(vv, 0.f);
            outB[(size_t)r * 512 + col] = f2b(vv);
          }
        }
      }
    }
  } else {
    // bias + residual (bf16)
#pragma unroll
    for (int rt = 0; rt < 2; rt++) {
      const int rbase = n0 + rt * 16 + hq * 4;
#pragma unroll
      for (int ct = 0; ct < 8; ct++) {
        const int col = ct * 16 + lq;
        const float bs = bias[col];
#pragma unroll
        for (int j = 0; j < 4; j++) {
          const int r = rbase + j;
          float rv = (r < NN) ? b2f(resB[(size_t)r * DD + col]) : 0.f;
          acc[rt][ct][j] += bs + rv;
        }
      }
    }
    // per-row LayerNorm: row's 128 cols = 8 ct regs x 16 lanes (same hq group)
#pragma unroll
    for (int rt = 0; rt < 2; rt++) {
      const int rbase = n0 + rt * 16 + hq * 4;
#pragma unroll
      for (int j = 0; j < 4; j++) {
        float s = 0.f;
#pragma unroll
        for (int ct = 0; ct < 8; ct++) s += acc[rt][ct][j];
        s += __shfl_xor(s, 1, 64); s += __shfl_xor(s, 2, 64);
        s += __shfl_xor(s, 4, 64); s += __shfl_xor(s, 8, 64);
        const float mu = s * (1.f / 128.f);
        float vs = 0.f;
#pragma unroll
        for (int ct = 0; ct < 8; ct++) { float d = acc[rt][ct][j] - mu; vs += d * d; }
        vs += __shfl_xor(vs, 1, 64); vs += __shfl_xor(vs, 2, 64);
        vs += __shfl_xor(vs, 4, 64); vs += __shfl_xor(vs, 8, 64);
        const float rs = rsqrtf(vs * (1.f / 128.f) + EPSF);
        const int r = rbase + j;
        if (r < NN) {
#pragma unroll
          for (int ct = 0; ct < 8; ct++) {
            const int col = ct * 16 + lq;
            float yv = (acc[rt][ct][j] - mu) * rs * lw[col] + lb[col];
            if (MODE == 2) outF[(size_t)r * DD + col] = yv;
            else           outB[(size_t)r * DD + col] = f2b(yv);
          }
        }
      }
    }
  }
}

// ---------------- single-pass fused attention (unroll x2 for load ILP) ----------------
// qkvsb [N,512] bf16: q 0:128, k 128:256, v 256:384, skip 384:512 (conv in-place).
__global__ __launch_bounds__(256) void k_attn(const int* __restrict__ csr_src,
                                              const int* __restrict__ rowptr,
                                              unsigned short* qkvsb) {
  const int l = threadIdx.x & 31;
  const int node = blockIdx.x * 8 + (threadIdx.x >> 5);  // grid exact: 12500*8
  const int row0 = rowptr[node], row1 = rowptr[node + 1];
  ushort4 qu = *(const ushort4*)&qkvsb[(size_t)node * 512 + l * 4];
  const float qx = b2f(qu.x), qy = b2f(qu.y), qz = b2f(qu.z), qw = b2f(qu.w);
  float ax = 0.f, ay = 0.f, az = 0.f, aw = 0.f, z = 0.f;
  int p = row0;
  for (; p + 2 <= row1; p += 2) {
    int s0 = csr_src[p], s1 = csr_src[p + 1];
    const unsigned short* b0 = &qkvsb[(size_t)s0 * 512];
    const unsigned short* b1 = &qkvsb[(size_t)s1 * 512];
    ushort4 k0 = *(const ushort4*)(b0 + 128 + l * 4);
    ushort4 v0 = *(const ushort4*)(b0 + 256 + l * 4);
    ushort4 k1 = *(const ushort4*)(b1 + 128 + l * 4);
    ushort4 v1 = *(const ushort4*)(b1 + 256 + l * 4);
    float d0 = qx * b2f(k0.x) + qy * b2f(k0.y) + qz * b2f(k0.z) + qw * b2f(k0.w);
    float d1 = qx * b2f(k1.x) + qy * b2f(k1.y) + qz * b2f(k1.z) + qw * b2f(k1.w);
    d0 += __shfl_xor(d0, 1, 32); d1 += __shfl_xor(d1, 1, 32);
    d0 += __shfl_xor(d0, 2, 32); d1 += __shfl_xor(d1, 2, 32);
    d0 += __shfl_xor(d0, 4, 32); d1 += __shfl_xor(d1, 4, 32);
    float e0 = __expf(d0 * 0.17677669529663687f);
    float e1 = __expf(d1 * 0.17677669529663687f);
    z += e0 + e1;
    ax += e0 * b2f(v0.x) + e1 * b2f(v1.x);
    ay += e0 * b2f(v0.y) + e1 * b2f(v1.y);
    az += e0 * b2f(v0.z) + e1 * b2f(v1.z);
    aw += e0 * b2f(v0.w) + e1 * b2f(v1.w);
  }
  if (p < row1) {
    int s = csr_src[p];
    const unsigned short* base = &qkvsb[(size_t)s * 512];
    ushort4 kr = *(const ushort4*)(base + 128 + l * 4);
    ushort4 vr = *(const ushort4*)(base + 256 + l * 4);
    float d = qx * b2f(kr.x) + qy * b2f(kr.y) + qz * b2f(kr.z) + qw * b2f(kr.w);
    d += __shfl_xor(d, 1, 32);
    d += __shfl_xor(d, 2, 32);
    d += __shfl_xor(d, 4, 32);
    float e = __expf(d * 0.17677669529663687f);
    z += e;
    ax += e * b2f(vr.x); ay += e * b2f(vr.y);
    az += e * b2f(vr.z); aw += e * b2f(vr.w);
  }
  const float rz = (z > 0.f) ? (1.f / z) : 0.f;  // guard in-degree-0 nodes
  ushort4 su = *(const ushort4*)&qkvsb[(size_t)node * 512 + 384 + l * 4];
  ushort4 o;
  o.x = f2b(b2f(su.x) + ax * rz);
  o.y = f2b(b2f(su.y) + ay * rz);
  o.z = f2b(b2f(su.z) + az * rz);
  o.w = f2b(b2f(su.w) + aw * rz);
  *(ushort4*)&qkvsb[(size_t)node * 512 + 384 + l * 4] = o;
}

extern "C" void kernel_launch(void* const* d_in, const int* in_sizes, int n_in,
                              void* d_out, int out_size, void* d_ws, size_t ws_size,
                              hipStream_t stream) {
  const float* x   = (const float*)d_in[0];
  const int*   ei  = (const int*)d_in[1];
  const float* Wq  = (const float*)d_in[2];
  const float* bq  = (const float*)d_in[3];
  const float* Wk  = (const float*)d_in[4];
  const float* bk  = (const float*)d_in[5];
  const float* Wv  = (const float*)d_in[6];
  const float* bv  = (const float*)d_in[7];
  const float* Wsk = (const float*)d_in[8];
  const float* bsk = (const float*)d_in[9];
  const float* Wo  = (const float*)d_in[10];
  const float* bo  = (const float*)d_in[11];
  const float* l1w = (const float*)d_in[12];
  const float* l1b = (const float*)d_in[13];
  const float* l2w = (const float*)d_in[14];
  const float* l2b = (const float*)d_in[15];
  const float* W1  = (const float*)d_in[16];
  const float* b1  = (const float*)d_in[17];
  const float* W2  = (const float*)d_in[18];
  const float* b2  = (const float*)d_in[19];

  // ---- workspace layout (~158 MB peak) ----
  unsigned short* wsu = (unsigned short*)d_ws;
  unsigned short* qkvsb = wsu;                           // [N,512] bf16 (later: hid)
  unsigned short* out2b = wsu + (size_t)NN * 512;        // [N,128] bf16
  unsigned short* xb    = out2b + (size_t)NN * DD;       // [N,128] bf16
  int* csr_src = (int*)(xb + (size_t)NN * DD);           // NE
  int* rowptr  = csr_src + NE;                           // N+1
  int* cnt     = rowptr + NN + 1;                        // N
  int* part    = cnt + NN;                               // 391
  int* partx   = part + 512;                             // 512
  size_t woff = (size_t)((partx + 512) - (int*)d_ws);
  woff = (woff + 3) & ~(size_t)3;                        // 16B-align weights
  unsigned short* Wqkvs = (unsigned short*)((int*)d_ws + woff);  // [512,128]
  unsigned short* Wob   = Wqkvs + 512 * DD;                      // [128,128]
  unsigned short* W1b   = Wob + DD * DD;                         // [512,128]
  unsigned short* W2b   = W1b + (size_t)HIDD * DD;               // [128,512]
  float* bias512        = (float*)(W2b + (size_t)DD * HIDD);

  unsigned short* hid = qkvsb;  // qkvsb dead after out-proj
  float* outf = (float*)d_out;

  const int GX = (NN + 127) / 128;  // 782
  dim3 blk(256);

  // x -> bf16 once; weights/biases cast+pack (one launch)
  k_cast<<<dim3(12500), blk, 0, stream>>>(x, xb, NN * DD);
  k_castw<<<dim3(209), blk, 0, stream>>>(Wq, Wk, Wv, Wsk, Wo, W1, W2, bq, bk, bv, bsk,
                                         Wqkvs, Wob, W1b, W2b, bias512);

  // CSR build
  k_zero_cnt<<<dim3(391), blk, 0, stream>>>(cnt);
  k_count<<<dim3(1954), blk, 0, stream>>>(ei, cnt);
  k_scan1<<<dim3(391), blk, 0, stream>>>(cnt, rowptr, part);
  k_scan2<<<dim3(1), dim3(512), 0, stream>>>(part, partx);
  k_scan3<<<dim3(391), blk, 0, stream>>>(rowptr, partx, cnt);
  k_scatter<<<dim3(1954), blk, 0, stream>>>(ei, cnt, csr_src);

  // fused q|k|v|skip projection: xb -> qkvsb bf16 [N,512]  (col-group-fastest 1D grid)
  k_gemm_wl<128, 128, false, 0><<<dim3(GX * 4), blk, 0, stream>>>(
      xb, Wqkvs, bias512, nullptr, nullptr, nullptr, nullptr, qkvsb);

  // single-pass attention (conv lands in skip slot)
  k_attn<<<dim3(12500), blk, 0, stream>>>(csr_src, rowptr, qkvsb);

  // out projection (A = conv slot, lda=512) + residual(xb) + LN1 -> out2b bf16
  k_gemm_wl<128, 512, false, 1><<<dim3(GX), blk, 0, stream>>>(
      qkvsb + 384, Wob, bo, xb, l1w, l1b, nullptr, out2b);

  // FFN1 (relu) -> hid bf16 [N,512]
  k_gemm_wl<128, 128, true, 0><<<dim3(GX * 4), blk, 0, stream>>>(
      out2b, W1b, b1, nullptr, nullptr, nullptr, nullptr, hid);

  // FFN2 (K=512) + residual(out2b) + LN2 -> d_out fp32
  k_gemm_wl<512, 512, false, 2><<<dim3(GX), blk, 0, stream>>>(
      hid, W2b, b2, out2b, l2w, l2b, outf, nullptr);
}

// Round 10
// 325.300 us; speedup vs baseline: 1.4741x; 1.0350x over previous
//
#include <hip/hip_runtime.h>

#define NN   100000
#define NE   500000
#define DD   128
#define HH   4
#define HIDD 512
#define EPSF 1e-5f

typedef __bf16 bf16x8 __attribute__((ext_vector_type(8)));
typedef float  f32x4  __attribute__((ext_vector_type(4)));

__device__ __forceinline__ unsigned short f2b(float f) {
  unsigned u = __float_as_uint(f);
  unsigned r = (u + 0x7FFFu + ((u >> 16) & 1)) >> 16;
  return (unsigned short)r;
}
__device__ __forceinline__ float b2f(unsigned short s) {
  return __uint_as_float(((unsigned)s) << 16);
}

// async global->LDS, 16B per lane; LDS dest is wave-uniform base (+lane*16 by HW)
#define GLOAD16(ldsp, gp) __builtin_amdgcn_global_load_lds(                      \
    (const __attribute__((address_space(1))) void*)(gp),                         \
    (__attribute__((address_space(3))) void*)(ldsp), 16, 0, 0)

// stage a 128x128 bf16 W tile: linear LDS dest, inverse-swizzled global source.
// read side uses slot (c16 ^ (row&15)); bank = slot*4 -> 16 distinct slots per group.
__device__ __forceinline__ void stageW(unsigned short* lds, const unsigned short* g,
                                       int ldg, int t) {
  const int w = t >> 6, l = t & 63;
#pragma unroll
  for (int i = 0; i < 8; i++) {
    const int chunk0 = i * 256 + w * 64;   // wave-uniform
    const int chunk = chunk0 + l;
    const int row = chunk >> 4, c16 = chunk & 15;
    const int gslot = c16 ^ (row & 15);
    GLOAD16(lds + (size_t)chunk0 * 8, g + (size_t)row * ldg + gslot * 8);
  }
}

// fp32 -> bf16 cast (x -> xb)
__global__ void k_cast(const float* __restrict__ src, unsigned short* __restrict__ dst, int n) {
  int i = (blockIdx.x * 256 + threadIdx.x) * 4;
  if (i >= n) return;
  float4 v = *(const float4*)&src[i];
  ushort4 o;
  o.x = f2b(v.x); o.y = f2b(v.y); o.z = f2b(v.z); o.w = f2b(v.w);
  *(ushort4*)&dst[i] = o;
}

// all weight casts + bias pack in ONE launch (209 blocks)
__global__ void k_castw(const float* __restrict__ Wq, const float* __restrict__ Wk,
                        const float* __restrict__ Wv, const float* __restrict__ Wsk,
                        const float* __restrict__ Wo, const float* __restrict__ W1,
                        const float* __restrict__ W2,
                        const float* __restrict__ bq, const float* __restrict__ bk,
                        const float* __restrict__ bv, const float* __restrict__ bs,
                        unsigned short* __restrict__ Wqkvs, unsigned short* __restrict__ Wob,
                        unsigned short* __restrict__ W1b, unsigned short* __restrict__ W2b,
                        float* __restrict__ bias512) {
  int i = blockIdx.x * 256 + threadIdx.x;
  if (i < 53248) {
    int e = i * 4;
    const float* src; unsigned short* dst; int off;
    if (e < 65536) {
      int seg = e >> 14;
      const float* s4[4] = {Wq, Wk, Wv, Wsk};
      src = s4[seg]; dst = Wqkvs + (seg << 14); off = e & 16383;
    } else if (e < 81920) { src = Wo;  dst = Wob; off = e - 65536; }
    else if (e < 147456)  { src = W1;  dst = W1b; off = e - 81920; }
    else                  { src = W2;  dst = W2b; off = e - 147456; }
    float4 v = *(const float4*)&src[off];
    ushort4 o; o.x = f2b(v.x); o.y = f2b(v.y); o.z = f2b(v.z); o.w = f2b(v.w);
    *(ushort4*)&dst[off] = o;
  } else if (i < 53376) {
    int b4 = (i - 53248) * 4;
    const float* srcs[4] = {bq, bk, bv, bs};
#pragma unroll
    for (int j = 0; j < 4; j++) {
      int idx = b4 + j;
      bias512[idx] = srcs[idx >> 7][idx & 127];
    }
  }
}

// ---------------- CSR build ----------------
__global__ void k_zero_cnt(int* __restrict__ cnt) {
  int i = blockIdx.x * 256 + threadIdx.x;
  if (i < NN) cnt[i] = 0;
}
__global__ void k_count(const int* __restrict__ ei, int* __restrict__ cnt) {
  int e = blockIdx.x * 256 + threadIdx.x;
  if (e < NE) atomicAdd(&cnt[ei[NE + e]], 1);
}
__global__ void k_scan1(const int* __restrict__ cnt, int* __restrict__ rowptr, int* __restrict__ part) {
  __shared__ int sh[256];
  int i = blockIdx.x * 256 + threadIdx.x;
  int v = (i < NN) ? cnt[i] : 0;
  sh[threadIdx.x] = v; __syncthreads();
  for (int off = 1; off < 256; off <<= 1) {
    int t = (threadIdx.x >= off) ? sh[threadIdx.x - off] : 0;
    __syncthreads();
    sh[threadIdx.x] += t;
    __syncthreads();
  }
  if (i < NN) rowptr[i] = sh[threadIdx.x] - v;  // exclusive
  if (threadIdx.x == 255) part[blockIdx.x] = sh[255];
}
__global__ void k_scan2(const int* __restrict__ part, int* __restrict__ partx) {
  __shared__ int sh[512];
  int t = threadIdx.x;
  int v = (t < 391) ? part[t] : 0;
  sh[t] = v; __syncthreads();
  for (int off = 1; off < 512; off <<= 1) {
    int u = (t >= off) ? sh[t - off] : 0;
    __syncthreads();
    sh[t] += u;
    __syncthreads();
  }
  partx[t] = sh[t] - v;
}
__global__ void k_scan3(int* __restrict__ rowptr, const int* __restrict__ partx, int* __restrict__ cnt) {
  int i = blockIdx.x * 256 + threadIdx.x;
  if (i < NN) {
    int r = rowptr[i] + partx[i >> 8];
    rowptr[i] = r;
    cnt[i] = r;
  }
  if (i == 0) rowptr[NN] = NE;
}
__global__ void k_scatter(const int* __restrict__ ei, int* __restrict__ cnt, int* __restrict__ csr_src) {
  int e = blockIdx.x * 256 + threadIdx.x;
  if (e >= NE) return;
  int d = ei[NE + e];
  int pos = atomicAdd(&cnt[d], 1);
  csr_src[pos] = ei[e];
}

// ---------------- GEMM: W in LDS (32KB), A global->reg, swapped-operand MFMA ----------------
// Block = 128 rows x 128 cols, 4 waves (each 32 rows).
// D layout after swap: x-row = lane&15 (fixed/lane), 4 consecutive cols in the 4 regs.
// MODE 0: 1D grid GX*4; b>>2 = row-tile, b&3 = col-group; out bf16 ldo=512.
// MODE 1: grid GX; + residual resB (bf16) + LN -> outB bf16 ldo=DD
// MODE 2: grid GX; + residual resB (bf16) + LN -> outF fp32 ldo=DD
template <int KTOT, int LDA, bool RELU, int MODE, int MW>
__global__ __launch_bounds__(256, MW) void k_gemm_wl(const unsigned short* __restrict__ A,
                                                     const unsigned short* __restrict__ W,
                                                     const float* __restrict__ bias,
                                                     const unsigned short* __restrict__ resB,
                                                     const float* __restrict__ lw,
                                                     const float* __restrict__ lb,
                                                     float* __restrict__ outF,
                                                     unsigned short* __restrict__ outB) {
  __shared__ __align__(16) unsigned short Ws[128 * 128];
  const int t = threadIdx.x;
  const int w = t >> 6, l = t & 63;
  const int bx   = (MODE == 0) ? (blockIdx.x >> 2) : blockIdx.x;
  const int col0 = (MODE == 0) ? (blockIdx.x & 3) * 128 : 0;
  const int n0 = bx * 128 + w * 32;  // this wave's first row
  const int lq = l & 15, hq = l >> 4;

#define LOADA2(dst, kb)                                                          \
  _Pragma("unroll") for (int ks = 0; ks < 4; ks++)                               \
    _Pragma("unroll") for (int rt = 0; rt < 2; rt++) {                           \
      const int row_ = n0 + rt * 16 + lq;                                        \
      bf16x8 zz = {};                                                            \
      dst[ks][rt] = (row_ < NN)                                                  \
          ? *(const bf16x8*)&A[(size_t)row_ * LDA + (kb) + ks * 32 + hq * 8]     \
          : zz;                                                                  \
    }

  f32x4 acc[2][8] = {};
  bf16x8 afr[4][2];
  LOADA2(afr, 0);
  stageW(Ws, W + (size_t)col0 * KTOT, KTOT, t);
  __syncthreads();
  constexpr int NC = KTOT / 128;
#pragma unroll
  for (int kc = 0; kc < NC; ++kc) {
    bf16x8 anx[4][2];
    if (kc + 1 < NC) LOADA2(anx, (kc + 1) * 128);  // prefetch overlaps MFMA below
#pragma unroll
    for (int ks = 0; ks < 4; ks++) {
      bf16x8 b[8];
      const int c16 = ks * 4 + hq;
#pragma unroll
      for (int ct = 0; ct < 8; ct++) {
        const int row = ct * 16 + lq;           // row&15 == lq
        b[ct] = *(const bf16x8*)&Ws[row * 128 + ((c16 ^ lq) * 8)];
      }
#pragma unroll
      for (int rt = 0; rt < 2; rt++)
#pragma unroll
        for (int ct = 0; ct < 8; ct++)
          acc[rt][ct] = __builtin_amdgcn_mfma_f32_16x16x32_bf16(b[ct], afr[ks][rt], acc[rt][ct], 0, 0, 0);
    }
    if (kc + 1 < NC) {
      __syncthreads();  // prior Ws readers done
      stageW(Ws, W + (size_t)col0 * KTOT + (kc + 1) * 128, KTOT, t);
      __syncthreads();  // next W ready (also drains anx)
#pragma unroll
      for (int ks = 0; ks < 4; ks++)
#pragma unroll
        for (int rt = 0; rt < 2; rt++) afr[ks][rt] = anx[ks][rt];
    }
  }

  if constexpr (MODE == 0) {
#pragma unroll
    for (int rt = 0; rt < 2; rt++) {
      const int row = n0 + rt * 16 + lq;
      if (row < NN) {
#pragma unroll
        for (int ct = 0; ct < 8; ct++) {
          const int col = col0 + ct * 16 + hq * 4;
          const float4 bs = *(const float4*)&bias[col];
          float v0 = acc[rt][ct][0] + bs.x, v1 = acc[rt][ct][1] + bs.y;
          float v2 = acc[rt][ct][2] + bs.z, v3 = acc[rt][ct][3] + bs.w;
          if (RELU) {
            v0 = fmaxf(v0, 0.f); v1 = fmaxf(v1, 0.f);
            v2 = fmaxf(v2, 0.f); v3 = fmaxf(v3, 0.f);
          }
          ushort4 o; o.x = f2b(v0); o.y = f2b(v1); o.z = f2b(v2); o.w = f2b(v3);
          *(ushort4*)&outB[(size_t)row * 512 + col] = o;
        }
      }
    }
  } else {
#pragma unroll
    for (int rt = 0; rt < 2; rt++) {
      const int row = n0 + rt * 16 + lq;
      // bias + residual (bf16, vector reads)
#pragma unroll
      for (int ct = 0; ct < 8; ct++) {
        const int col = ct * 16 + hq * 4;
        const float4 bs = *(const float4*)&bias[col];
        ushort4 rv = make_ushort4(0, 0, 0, 0);
        if (row < NN) rv = *(const ushort4*)&resB[(size_t)row * DD + col];
        acc[rt][ct][0] += bs.x + b2f(rv.x);
        acc[rt][ct][1] += bs.y + b2f(rv.y);
        acc[rt][ct][2] += bs.z + b2f(rv.z);
        acc[rt][ct][3] += bs.w + b2f(rv.w);
      }
      // LayerNorm: row's 128 cols = 32 in-lane regs x 4 hq-groups (lanes l, l^16, l^32)
      float s = 0.f;
#pragma unroll
      for (int ct = 0; ct < 8; ct++)
#pragma unroll
        for (int j = 0; j < 4; j++) s += acc[rt][ct][j];
      s += __shfl_xor(s, 16, 64); s += __shfl_xor(s, 32, 64);
      const float mu = s * (1.f / 128.f);
      float vs = 0.f;
#pragma unroll
      for (int ct = 0; ct < 8; ct++)
#pragma unroll
        for (int j = 0; j < 4; j++) { float d = acc[rt][ct][j] - mu; vs += d * d; }
      vs += __shfl_xor(vs, 16, 64); vs += __shfl_xor(vs, 32, 64);
      const float rs = rsqrtf(vs * (1.f / 128.f) + EPSF);
      if (row < NN) {
#pragma unroll
        for (int ct = 0; ct < 8; ct++) {
          const int col = ct * 16 + hq * 4;
          const float4 lw4 = *(const float4*)&lw[col];
          const float4 lb4 = *(const float4*)&lb[col];
          float y0 = (acc[rt][ct][0] - mu) * rs * lw4.x + lb4.x;
          float y1 = (acc[rt][ct][1] - mu) * rs * lw4.y + lb4.y;
          float y2 = (acc[rt][ct][2] - mu) * rs * lw4.z + lb4.z;
          float y3 = (acc[rt][ct][3] - mu) * rs * lw4.w + lb4.w;
          if (MODE == 2) {
            float4 o; o.x = y0; o.y = y1; o.z = y2; o.w = y3;
            *(float4*)&outF[(size_t)row * DD + col] = o;
          } else {
            ushort4 o; o.x = f2b(y0); o.y = f2b(y1); o.z = f2b(y2); o.w = f2b(y3);
            *(ushort4*)&outB[(size_t)row * DD + col] = o;
          }
        }
      }
    }
  }
#undef LOADA2
}

// ---------------- single-pass fused attention (unroll x2 for load ILP) ----------------
// qkvsb [N,512] bf16: q 0:128, k 128:256, v 256:384, skip 384:512 (conv in-place).
__global__ __launch_bounds__(256) void k_attn(const int* __restrict__ csr_src,
                                              const int* __restrict__ rowptr,
                                              unsigned short* qkvsb) {
  const int l = threadIdx.x & 31;
  const int node = blockIdx.x * 8 + (threadIdx.x >> 5);  // grid exact: 12500*8
  const int row0 = rowptr[node], row1 = rowptr[node + 1];
  ushort4 qu = *(const ushort4*)&qkvsb[(size_t)node * 512 + l * 4];
  const float qx = b2f(qu.x), qy = b2f(qu.y), qz = b2f(qu.z), qw = b2f(qu.w);
  float ax = 0.f, ay = 0.f, az = 0.f, aw = 0.f, z = 0.f;
  int p = row0;
  for (; p + 2 <= row1; p += 2) {
    int s0 = csr_src[p], s1 = csr_src[p + 1];
    const unsigned short* b0 = &qkvsb[(size_t)s0 * 512];
    const unsigned short* b1 = &qkvsb[(size_t)s1 * 512];
    ushort4 k0 = *(const ushort4*)(b0 + 128 + l * 4);
    ushort4 v0 = *(const ushort4*)(b0 + 256 + l * 4);
    ushort4 k1 = *(const ushort4*)(b1 + 128 + l * 4);
    ushort4 v1 = *(const ushort4*)(b1 + 256 + l * 4);
    float d0 = qx * b2f(k0.x) + qy * b2f(k0.y) + qz * b2f(k0.z) + qw * b2f(k0.w);
    float d1 = qx * b2f(k1.x) + qy * b2f(k1.y) + qz * b2f(k1.z) + qw * b2f(k1.w);
    d0 += __shfl_xor(d0, 1, 32); d1 += __shfl_xor(d1, 1, 32);
    d0 += __shfl_xor(d0, 2, 32); d1 += __shfl_xor(d1, 2, 32);
    d0 += __shfl_xor(d0, 4, 32); d1 += __shfl_xor(d1, 4, 32);
    float e0 = __expf(d0 * 0.17677669529663687f);
    float e1 = __expf(d1 * 0.17677669529663687f);
    z += e0 + e1;
    ax += e0 * b2f(v0.x) + e1 * b2f(v1.x);
    ay += e0 * b2f(v0.y) + e1 * b2f(v1.y);
    az += e0 * b2f(v0.z) + e1 * b2f(v1.z);
    aw += e0 * b2f(v0.w) + e1 * b2f(v1.w);
  }
  if (p < row1) {
    int s = csr_src[p];
    const unsigned short* base = &qkvsb[(size_t)s * 512];
    ushort4 kr = *(const ushort4*)(base + 128 + l * 4);
    ushort4 vr = *(const ushort4*)(base + 256 + l * 4);
    float d = qx * b2f(kr.x) + qy * b2f(kr.y) + qz * b2f(kr.z) + qw * b2f(kr.w);
    d += __shfl_xor(d, 1, 32);
    d += __shfl_xor(d, 2, 32);
    d += __shfl_xor(d, 4, 32);
    float e = __expf(d * 0.17677669529663687f);
    z += e;
    ax += e * b2f(vr.x); ay += e * b2f(vr.y);
    az += e * b2f(vr.z); aw += e * b2f(vr.w);
  }
  const float rz = (z > 0.f) ? (1.f / z) : 0.f;  // guard in-degree-0 nodes
  ushort4 su = *(const ushort4*)&qkvsb[(size_t)node * 512 + 384 + l * 4];
  ushort4 o;
  o.x = f2b(b2f(su.x) + ax * rz);
  o.y = f2b(b2f(su.y) + ay * rz);
  o.z = f2b(b2f(su.z) + az * rz);
  o.w = f2b(b2f(su.w) + aw * rz);
  *(ushort4*)&qkvsb[(size_t)node * 512 + 384 + l * 4] = o;
}

extern "C" void kernel_launch(void* const* d_in, const int* in_sizes, int n_in,
                              void* d_out, int out_size, void* d_ws, size_t ws_size,
                              hipStream_t stream) {
  const float* x   = (const float*)d_in[0];
  const int*   ei  = (const int*)d_in[1];
  const float* Wq  = (const float*)d_in[2];
  const float* bq  = (const float*)d_in[3];
  const float* Wk  = (const float*)d_in[4];
  const float* bk  = (const float*)d_in[5];
  const float* Wv  = (const float*)d_in[6];
  const float* bv  = (const float*)d_in[7];
  const float* Wsk = (const float*)d_in[8];
  const float* bsk = (const float*)d_in[9];
  const float* Wo  = (const float*)d_in[10];
  const float* bo  = (const float*)d_in[11];
  const float* l1w = (const float*)d_in[12];
  const float* l1b = (const float*)d_in[13];
  const float* l2w = (const float*)d_in[14];
  const float* l2b = (const float*)d_in[15];
  const float* W1  = (const float*)d_in[16];
  const float* b1  = (const float*)d_in[17];
  const float* W2  = (const float*)d_in[18];
  const float* b2  = (const float*)d_in[19];

  // ---- workspace layout (~158 MB peak) ----
  unsigned short* wsu = (unsigned short*)d_ws;
  unsigned short* qkvsb = wsu;                           // [N,512] bf16 (later: hid)
  unsigned short* out2b = wsu + (size_t)NN * 512;        // [N,128] bf16
  unsigned short* xb    = out2b + (size_t)NN * DD;       // [N,128] bf16
  int* csr_src = (int*)(xb + (size_t)NN * DD);           // NE
  int* rowptr  = csr_src + NE;                           // N+1
  int* cnt     = rowptr + NN + 1;                        // N
  int* part    = cnt + NN;                               // 391
  int* partx   = part + 512;                             // 512
  size_t woff = (size_t)((partx + 512) - (int*)d_ws);
  woff = (woff + 3) & ~(size_t)3;                        // 16B-align weights
  unsigned short* Wqkvs = (unsigned short*)((int*)d_ws + woff);  // [512,128]
  unsigned short* Wob   = Wqkvs + 512 * DD;                      // [128,128]
  unsigned short* W1b   = Wob + DD * DD;                         // [512,128]
  unsigned short* W2b   = W1b + (size_t)HIDD * DD;               // [128,512]
  float* bias512        = (float*)(W2b + (size_t)DD * HIDD);

  unsigned short* hid = qkvsb;  // qkvsb dead after out-proj
  float* outf = (float*)d_out;

  const int GX = (NN + 127) / 128;  // 782
  dim3 blk(256);

  // x -> bf16 once; weights/biases cast+pack (one launch)
  k_cast<<<dim3(12500), blk, 0, stream>>>(x, xb, NN * DD);
  k_castw<<<dim3(209), blk, 0, stream>>>(Wq, Wk, Wv, Wsk, Wo, W1, W2, bq, bk, bv, bsk,
                                         Wqkvs, Wob, W1b, W2b, bias512);

  // CSR build
  k_zero_cnt<<<dim3(391), blk, 0, stream>>>(cnt);
  k_count<<<dim3(1954), blk, 0, stream>>>(ei, cnt);
  k_scan1<<<dim3(391), blk, 0, stream>>>(cnt, rowptr, part);
  k_scan2<<<dim3(1), dim3(512), 0, stream>>>(part, partx);
  k_scan3<<<dim3(391), blk, 0, stream>>>(rowptr, partx, cnt);
  k_scatter<<<dim3(1954), blk, 0, stream>>>(ei, cnt, csr_src);

  // fused q|k|v|skip projection: xb -> qkvsb bf16 [N,512]  (col-group-fastest 1D grid)
  k_gemm_wl<128, 128, false, 0, 4><<<dim3(GX * 4), blk, 0, stream>>>(
      xb, Wqkvs, bias512, nullptr, nullptr, nullptr, nullptr, qkvsb);

  // single-pass attention (conv lands in skip slot)
  k_attn<<<dim3(12500), blk, 0, stream>>>(csr_src, rowptr, qkvsb);

  // out projection (A = conv slot, lda=512) + residual(xb) + LN1 -> out2b bf16
  k_gemm_wl<128, 512, false, 1, 4><<<dim3(GX), blk, 0, stream>>>(
      qkvsb + 384, Wob, bo, xb, l1w, l1b, nullptr, out2b);

  // FFN1 (relu) -> hid bf16 [N,512]
  k_gemm_wl<128, 128, true, 0, 4><<<dim3(GX * 4), blk, 0, stream>>>(
      out2b, W1b, b1, nullptr, nullptr, nullptr, nullptr, hid);

  // FFN2 (K=512, A-prefetch pipeline) + residual(out2b) + LN2 -> d_out fp32
  k_gemm_wl<512, 512, false, 2, 3><<<dim3(GX), blk, 0, stream>>>(
      hid, W2b, b2, out2b, l2w, l2b, outf, nullptr);
}

// Round 11
// 271.665 us; speedup vs baseline: 1.7651x; 1.1974x over previous
//
#include <hip/hip_runtime.h>

#define NN   100000
#define NE   500000
#define DD   128
#define HH   4
#define HIDD 512
#define EPSF 1e-5f

typedef __bf16 bf16x8 __attribute__((ext_vector_type(8)));
typedef float  f32x4  __attribute__((ext_vector_type(4)));

__device__ __forceinline__ unsigned short f2b(float f) {
  unsigned u = __float_as_uint(f);
  unsigned r = (u + 0x7FFFu + ((u >> 16) & 1)) >> 16;
  return (unsigned short)r;
}
__device__ __forceinline__ float b2f(unsigned short s) {
  return __uint_as_float(((unsigned)s) << 16);
}

// async global->LDS, 16B per lane; LDS dest is wave-uniform base (+lane*16 by HW)
#define GLOAD16(ldsp, gp) __builtin_amdgcn_global_load_lds(                      \
    (const __attribute__((address_space(1))) void*)(gp),                         \
    (__attribute__((address_space(3))) void*)(ldsp), 16, 0, 0)

// stage a 128x128 bf16 tile: linear LDS dest, inverse-swizzled global source.
// read side uses 16B slot (c16 ^ (row&15)).
__device__ __forceinline__ void stageW(unsigned short* lds, const unsigned short* g,
                                       int ldg, int t) {
  const int w = t >> 6, l = t & 63;
#pragma unroll
  for (int i = 0; i < 8; i++) {
    const int chunk0 = i * 256 + w * 64;   // wave-uniform
    const int chunk = chunk0 + l;
    const int row = chunk >> 4, c16 = chunk & 15;
    const int gslot = c16 ^ (row & 15);
    GLOAD16(lds + (size_t)chunk0 * 8, g + (size_t)row * ldg + gslot * 8);
  }
}

// fp32 -> bf16 cast (x -> xb)
__global__ void k_cast(const float* __restrict__ src, unsigned short* __restrict__ dst, int n) {
  int i = (blockIdx.x * 256 + threadIdx.x) * 4;
  if (i >= n) return;
  float4 v = *(const float4*)&src[i];
  ushort4 o;
  o.x = f2b(v.x); o.y = f2b(v.y); o.z = f2b(v.z); o.w = f2b(v.w);
  *(ushort4*)&dst[i] = o;
}

// all weight casts + bias pack in ONE launch (209 blocks)
__global__ void k_castw(const float* __restrict__ Wq, const float* __restrict__ Wk,
                        const float* __restrict__ Wv, const float* __restrict__ Wsk,
                        const float* __restrict__ Wo, const float* __restrict__ W1,
                        const float* __restrict__ W2,
                        const float* __restrict__ bq, const float* __restrict__ bk,
                        const float* __restrict__ bv, const float* __restrict__ bs,
                        unsigned short* __restrict__ Wqkvs, unsigned short* __restrict__ Wob,
                        unsigned short* __restrict__ W1b, unsigned short* __restrict__ W2b,
                        float* __restrict__ bias512) {
  int i = blockIdx.x * 256 + threadIdx.x;
  if (i < 53248) {
    int e = i * 4;
    const float* src; unsigned short* dst; int off;
    if (e < 65536) {
      int seg = e >> 14;
      const float* s4[4] = {Wq, Wk, Wv, Wsk};
      src = s4[seg]; dst = Wqkvs + (seg << 14); off = e & 16383;
    } else if (e < 81920) { src = Wo;  dst = Wob; off = e - 65536; }
    else if (e < 147456)  { src = W1;  dst = W1b; off = e - 81920; }
    else                  { src = W2;  dst = W2b; off = e - 147456; }
    float4 v = *(const float4*)&src[off];
    ushort4 o; o.x = f2b(v.x); o.y = f2b(v.y); o.z = f2b(v.z); o.w = f2b(v.w);
    *(ushort4*)&dst[off] = o;
  } else if (i < 53376) {
    int b4 = (i - 53248) * 4;
    const float* srcs[4] = {bq, bk, bv, bs};
#pragma unroll
    for (int j = 0; j < 4; j++) {
      int idx = b4 + j;
      bias512[idx] = srcs[idx >> 7][idx & 127];
    }
  }
}

// ---------------- CSR build ----------------
__global__ void k_zero_cnt(int* __restrict__ cnt) {
  int i = blockIdx.x * 256 + threadIdx.x;
  if (i < NN) cnt[i] = 0;
}
__global__ void k_count(const int* __restrict__ ei, int* __restrict__ cnt) {
  int e = blockIdx.x * 256 + threadIdx.x;
  if (e < NE) atomicAdd(&cnt[ei[NE + e]], 1);
}
__global__ void k_scan1(const int* __restrict__ cnt, int* __restrict__ rowptr, int* __restrict__ part) {
  __shared__ int sh[256];
  int i = blockIdx.x * 256 + threadIdx.x;
  int v = (i < NN) ? cnt[i] : 0;
  sh[threadIdx.x] = v; __syncthreads();
  for (int off = 1; off < 256; off <<= 1) {
    int t = (threadIdx.x >= off) ? sh[threadIdx.x - off] : 0;
    __syncthreads();
    sh[threadIdx.x] += t;
    __syncthreads();
  }
  if (i < NN) rowptr[i] = sh[threadIdx.x] - v;  // exclusive
  if (threadIdx.x == 255) part[blockIdx.x] = sh[255];
}
__global__ void k_scan2(const int* __restrict__ part, int* __restrict__ partx) {
  __shared__ int sh[512];
  int t = threadIdx.x;
  int v = (t < 391) ? part[t] : 0;
  sh[t] = v; __syncthreads();
  for (int off = 1; off < 512; off <<= 1) {
    int u = (t >= off) ? sh[t - off] : 0;
    __syncthreads();
    sh[t] += u;
    __syncthreads();
  }
  partx[t] = sh[t] - v;
}
__global__ void k_scan3(int* __restrict__ rowptr, const int* __restrict__ partx, int* __restrict__ cnt) {
  int i = blockIdx.x * 256 + threadIdx.x;
  if (i < NN) {
    int r = rowptr[i] + partx[i >> 8];
    rowptr[i] = r;
    cnt[i] = r;
  }
  if (i == 0) rowptr[NN] = NE;
}
__global__ void k_scatter(const int* __restrict__ ei, int* __restrict__ cnt, int* __restrict__ csr_src) {
  int e = blockIdx.x * 256 + threadIdx.x;
  if (e >= NE) return;
  int d = ei[NE + e];
  int pos = atomicAdd(&cnt[d], 1);
  csr_src[pos] = ei[e];
}

// load the 8 A-fragments for a 32-row wave directly global->reg (predicated)
#define LOADA(dst, Aptr, LDA_, kb)                                               \
  _Pragma("unroll") for (int ks = 0; ks < 4; ks++)                               \
    _Pragma("unroll") for (int rt = 0; rt < 2; rt++) {                           \
      const int row_ = n0 + rt * 16 + lq;                                        \
      bf16x8 zz = {};                                                            \
      dst[ks][rt] = (row_ < NN)                                                  \
          ? *(const bf16x8*)&(Aptr)[(size_t)row_ * (LDA_) + (kb) + ks * 32 + hq * 8] \
          : zz;                                                                  \
    }

// ---------------- qkvs: A staged in regs once, loop 4 W col-groups ----------------
// Block = 128 rows; out bf16 [N,512].
__global__ __launch_bounds__(256, 2) void k_gemm_cg(const unsigned short* __restrict__ A,
                                                    const unsigned short* __restrict__ W,
                                                    const float* __restrict__ bias,
                                                    unsigned short* __restrict__ outB) {
  __shared__ __align__(16) unsigned short Ws[128 * 128];
  const int t = threadIdx.x;
  const int w = t >> 6, l = t & 63;
  const int n0 = blockIdx.x * 128 + w * 32;
  const int lq = l & 15, hq = l >> 4;

  bf16x8 af[4][2];
  LOADA(af, A, 128, 0);
#pragma unroll 1
  for (int cg = 0; cg < 4; ++cg) {
    if (cg) __syncthreads();              // prior Ws readers done
    stageW(Ws, W + (size_t)cg * 128 * 128, 128, t);
    __syncthreads();                      // Ws ready (drains af loads too)
    f32x4 acc[2][8] = {};
#pragma unroll
    for (int ks = 0; ks < 4; ks++) {
      bf16x8 b[8];
      const int c16 = ks * 4 + hq;
#pragma unroll
      for (int ct = 0; ct < 8; ct++) {
        const int row = ct * 16 + lq;
        b[ct] = *(const bf16x8*)&Ws[row * 128 + ((c16 ^ lq) * 8)];
      }
#pragma unroll
      for (int rt = 0; rt < 2; rt++)
#pragma unroll
        for (int ct = 0; ct < 8; ct++)
          acc[rt][ct] = __builtin_amdgcn_mfma_f32_16x16x32_bf16(b[ct], af[ks][rt], acc[rt][ct], 0, 0, 0);
    }
#pragma unroll
    for (int rt = 0; rt < 2; rt++) {
      const int row = n0 + rt * 16 + lq;
      if (row < NN) {
#pragma unroll
        for (int ct = 0; ct < 8; ct++) {
          const int col = cg * 128 + ct * 16 + hq * 4;
          const float4 bs = *(const float4*)&bias[col];
          ushort4 o;
          o.x = f2b(acc[rt][ct][0] + bs.x);
          o.y = f2b(acc[rt][ct][1] + bs.y);
          o.z = f2b(acc[rt][ct][2] + bs.z);
          o.w = f2b(acc[rt][ct][3] + bs.w);
          *(ushort4*)&outB[(size_t)row * 512 + col] = o;
        }
      }
    }
  }
}

// ---------------- out-proj GEMM (K=128) + residual + LN -> bf16 ----------------
__global__ __launch_bounds__(256, 4) void k_gemm_ln1(const unsigned short* __restrict__ A,
                                                     const unsigned short* __restrict__ W,
                                                     const float* __restrict__ bias,
                                                     const unsigned short* __restrict__ resB,
                                                     const float* __restrict__ lw,
                                                     const float* __restrict__ lb,
                                                     unsigned short* __restrict__ outB) {
  __shared__ __align__(16) unsigned short Ws[128 * 128];
  const int t = threadIdx.x;
  const int w = t >> 6, l = t & 63;
  const int n0 = blockIdx.x * 128 + w * 32;
  const int lq = l & 15, hq = l >> 4;

  bf16x8 af[4][2];
  LOADA(af, A, 512, 0);
  stageW(Ws, W, 128, t);
  __syncthreads();
  f32x4 acc[2][8] = {};
#pragma unroll
  for (int ks = 0; ks < 4; ks++) {
    bf16x8 b[8];
    const int c16 = ks * 4 + hq;
#pragma unroll
    for (int ct = 0; ct < 8; ct++) {
      const int row = ct * 16 + lq;
      b[ct] = *(const bf16x8*)&Ws[row * 128 + ((c16 ^ lq) * 8)];
    }
#pragma unroll
    for (int rt = 0; rt < 2; rt++)
#pragma unroll
      for (int ct = 0; ct < 8; ct++)
        acc[rt][ct] = __builtin_amdgcn_mfma_f32_16x16x32_bf16(b[ct], af[ks][rt], acc[rt][ct], 0, 0, 0);
  }
#pragma unroll
  for (int rt = 0; rt < 2; rt++) {
    const int row = n0 + rt * 16 + lq;
#pragma unroll
    for (int ct = 0; ct < 8; ct++) {
      const int col = ct * 16 + hq * 4;
      const float4 bs = *(const float4*)&bias[col];
      ushort4 rv = make_ushort4(0, 0, 0, 0);
      if (row < NN) rv = *(const ushort4*)&resB[(size_t)row * DD + col];
      acc[rt][ct][0] += bs.x + b2f(rv.x);
      acc[rt][ct][1] += bs.y + b2f(rv.y);
      acc[rt][ct][2] += bs.z + b2f(rv.z);
      acc[rt][ct][3] += bs.w + b2f(rv.w);
    }
    float s = 0.f;
#pragma unroll
    for (int ct = 0; ct < 8; ct++)
#pragma unroll
      for (int j = 0; j < 4; j++) s += acc[rt][ct][j];
    s += __shfl_xor(s, 16, 64); s += __shfl_xor(s, 32, 64);
    const float mu = s * (1.f / 128.f);
    float vs = 0.f;
#pragma unroll
    for (int ct = 0; ct < 8; ct++)
#pragma unroll
      for (int j = 0; j < 4; j++) { float d = acc[rt][ct][j] - mu; vs += d * d; }
    vs += __shfl_xor(vs, 16, 64); vs += __shfl_xor(vs, 32, 64);
    const float rs = rsqrtf(vs * (1.f / 128.f) + EPSF);
    if (row < NN) {
#pragma unroll
      for (int ct = 0; ct < 8; ct++) {
        const int col = ct * 16 + hq * 4;
        const float4 lw4 = *(const float4*)&lw[col];
        const float4 lb4 = *(const float4*)&lb[col];
        ushort4 o;
        o.x = f2b((acc[rt][ct][0] - mu) * rs * lw4.x + lb4.x);
        o.y = f2b((acc[rt][ct][1] - mu) * rs * lw4.y + lb4.y);
        o.z = f2b((acc[rt][ct][2] - mu) * rs * lw4.z + lb4.z);
        o.w = f2b((acc[rt][ct][3] - mu) * rs * lw4.w + lb4.w);
        *(ushort4*)&outB[(size_t)row * DD + col] = o;
      }
    }
  }
}

// ---------------- fused FFN: relu(out2b@W1^T+b1)@W2^T + b2 + out2b -> LN2 -> d_out ----------------
// hid never touches HBM: per col-group, FFN1 acc -> bf16 -> swizzled LDS bounce (Hs)
// -> FFN2 A-fragments. Ws (32KB) shared by W1[cg] then W2[:,cg-chunk]. LDS 64KB.
__global__ __launch_bounds__(256, 2) void k_ffn_fused(const unsigned short* __restrict__ A,
                                                      const unsigned short* __restrict__ W1,
                                                      const float* __restrict__ b1,
                                                      const unsigned short* __restrict__ W2,
                                                      const float* __restrict__ b2,
                                                      const float* __restrict__ lw,
                                                      const float* __restrict__ lb,
                                                      float* __restrict__ outF) {
  __shared__ __align__(16) unsigned short Ws[128 * 128];
  __shared__ __align__(16) unsigned short Hs[128 * 128];
  const int t = threadIdx.x;
  const int w = t >> 6, l = t & 63;
  const int n0 = blockIdx.x * 128 + w * 32;
  const int lq = l & 15, hq = l >> 4;
  const int lrow = w * 32;  // wave's local row base in Hs

  bf16x8 af[4][2];
  LOADA(af, A, 128, 0);

  f32x4 acc2[2][8] = {};
#pragma unroll 1
  for (int cg = 0; cg < 4; ++cg) {
    if (cg) __syncthreads();              // prev FFN2 done reading Ws & Hs
    stageW(Ws, W1 + (size_t)cg * 128 * 128, 128, t);
    __syncthreads();                      // W1[cg] ready
    // FFN1: acc1 = A @ W1[cg]^T
    f32x4 acc1[2][8] = {};
#pragma unroll
    for (int ks = 0; ks < 4; ks++) {
      bf16x8 b[8];
      const int c16 = ks * 4 + hq;
#pragma unroll
      for (int ct = 0; ct < 8; ct++) {
        const int row = ct * 16 + lq;
        b[ct] = *(const bf16x8*)&Ws[row * 128 + ((c16 ^ lq) * 8)];
      }
#pragma unroll
      for (int rt = 0; rt < 2; rt++)
#pragma unroll
        for (int ct = 0; ct < 8; ct++)
          acc1[rt][ct] = __builtin_amdgcn_mfma_f32_16x16x32_bf16(b[ct], af[ks][rt], acc1[rt][ct], 0, 0, 0);
    }
    // relu+bias -> bf16 -> Hs bounce (swizzled 16B slots: slot ^ (row&15))
#pragma unroll
    for (int rt = 0; rt < 2; rt++) {
      const int row = lrow + rt * 16 + lq;
#pragma unroll
      for (int ct = 0; ct < 8; ct++) {
        const int col = ct * 16 + hq * 4;
        const float4 bs = *(const float4*)&b1[cg * 128 + col];
        ushort4 o;
        o.x = f2b(fmaxf(acc1[rt][ct][0] + bs.x, 0.f));
        o.y = f2b(fmaxf(acc1[rt][ct][1] + bs.y, 0.f));
        o.z = f2b(fmaxf(acc1[rt][ct][2] + bs.z, 0.f));
        o.w = f2b(fmaxf(acc1[rt][ct][3] + bs.w, 0.f));
        *(ushort4*)&Hs[row * 128 + (((col >> 3) ^ lq) * 8) + (col & 7)] = o;
      }
    }
    __syncthreads();                      // Hs visible; FFN1's Ws reads done
    stageW(Ws, W2 + (size_t)cg * 128, 512, t);
    __syncthreads();                      // W2 chunk ready
    // FFN2 partial: acc2 += hid[:, cg*128..] @ W2[:, cg*128..]^T
#pragma unroll
    for (int ks = 0; ks < 4; ks++) {
      bf16x8 b[8];
      const int c16 = ks * 4 + hq;
#pragma unroll
      for (int ct = 0; ct < 8; ct++) {
        const int row = ct * 16 + lq;
        b[ct] = *(const bf16x8*)&Ws[row * 128 + ((c16 ^ lq) * 8)];
      }
      bf16x8 h[2];
#pragma unroll
      for (int rt = 0; rt < 2; rt++) {
        const int row = lrow + rt * 16 + lq;
        h[rt] = *(const bf16x8*)&Hs[row * 128 + (((ks * 4 + hq) ^ lq) * 8)];
      }
#pragma unroll
      for (int rt = 0; rt < 2; rt++)
#pragma unroll
        for (int ct = 0; ct < 8; ct++)
          acc2[rt][ct] = __builtin_amdgcn_mfma_f32_16x16x32_bf16(b[ct], h[rt], acc2[rt][ct], 0, 0, 0);
    }
  }

  // epilogue: bias2 + residual(out2b) + LN2 -> fp32 d_out
#pragma unroll
  for (int rt = 0; rt < 2; rt++) {
    const int row = n0 + rt * 16 + lq;
#pragma unroll
    for (int ct = 0; ct < 8; ct++) {
      const int col = ct * 16 + hq * 4;
      const float4 bs = *(const float4*)&b2[col];
      ushort4 rv = make_ushort4(0, 0, 0, 0);
      if (row < NN) rv = *(const ushort4*)&A[(size_t)row * DD + col];
      acc2[rt][ct][0] += bs.x + b2f(rv.x);
      acc2[rt][ct][1] += bs.y + b2f(rv.y);
      acc2[rt][ct][2] += bs.z + b2f(rv.z);
      acc2[rt][ct][3] += bs.w + b2f(rv.w);
    }
    float s = 0.f;
#pragma unroll
    for (int ct = 0; ct < 8; ct++)
#pragma unroll
      for (int j = 0; j < 4; j++) s += acc2[rt][ct][j];
    s += __shfl_xor(s, 16, 64); s += __shfl_xor(s, 32, 64);
    const float mu = s * (1.f / 128.f);
    float vs = 0.f;
#pragma unroll
    for (int ct = 0; ct < 8; ct++)
#pragma unroll
      for (int j = 0; j < 4; j++) { float d = acc2[rt][ct][j] - mu; vs += d * d; }
    vs += __shfl_xor(vs, 16, 64); vs += __shfl_xor(vs, 32, 64);
    const float rs = rsqrtf(vs * (1.f / 128.f) + EPSF);
    if (row < NN) {
#pragma unroll
      for (int ct = 0; ct < 8; ct++) {
        const int col = ct * 16 + hq * 4;
        const float4 lw4 = *(const float4*)&lw[col];
        const float4 lb4 = *(const float4*)&lb[col];
        float4 o;
        o.x = (acc2[rt][ct][0] - mu) * rs * lw4.x + lb4.x;
        o.y = (acc2[rt][ct][1] - mu) * rs * lw4.y + lb4.y;
        o.z = (acc2[rt][ct][2] - mu) * rs * lw4.z + lb4.z;
        o.w = (acc2[rt][ct][3] - mu) * rs * lw4.w + lb4.w;
        *(float4*)&outF[(size_t)row * DD + col] = o;
      }
    }
  }
}

// ---------------- single-pass fused attention (unroll x2 for load ILP) ----------------
// qkvsb [N,512] bf16: q 0:128, k 128:256, v 256:384, skip 384:512 (conv in-place).
__global__ __launch_bounds__(256) void k_attn(const int* __restrict__ csr_src,
                                              const int* __restrict__ rowptr,
                                              unsigned short* qkvsb) {
  const int l = threadIdx.x & 31;
  const int node = blockIdx.x * 8 + (threadIdx.x >> 5);  // grid exact: 12500*8
  const int row0 = rowptr[node], row1 = rowptr[node + 1];
  ushort4 qu = *(const ushort4*)&qkvsb[(size_t)node * 512 + l * 4];
  const float qx = b2f(qu.x), qy = b2f(qu.y), qz = b2f(qu.z), qw = b2f(qu.w);
  float ax = 0.f, ay = 0.f, az = 0.f, aw = 0.f, z = 0.f;
  int p = row0;
  for (; p + 2 <= row1; p += 2) {
    int s0 = csr_src[p], s1 = csr_src[p + 1];
    const unsigned short* b0 = &qkvsb[(size_t)s0 * 512];
    const unsigned short* b1 = &qkvsb[(size_t)s1 * 512];
    ushort4 k0 = *(const ushort4*)(b0 + 128 + l * 4);
    ushort4 v0 = *(const ushort4*)(b0 + 256 + l * 4);
    ushort4 k1 = *(const ushort4*)(b1 + 128 + l * 4);
    ushort4 v1 = *(const ushort4*)(b1 + 256 + l * 4);
    float d0 = qx * b2f(k0.x) + qy * b2f(k0.y) + qz * b2f(k0.z) + qw * b2f(k0.w);
    float d1 = qx * b2f(k1.x) + qy * b2f(k1.y) + qz * b2f(k1.z) + qw * b2f(k1.w);
    d0 += __shfl_xor(d0, 1, 32); d1 += __shfl_xor(d1, 1, 32);
    d0 += __shfl_xor(d0, 2, 32); d1 += __shfl_xor(d1, 2, 32);
    d0 += __shfl_xor(d0, 4, 32); d1 += __shfl_xor(d1, 4, 32);
    float e0 = __expf(d0 * 0.17677669529663687f);
    float e1 = __expf(d1 * 0.17677669529663687f);
    z += e0 + e1;
    ax += e0 * b2f(v0.x) + e1 * b2f(v1.x);
    ay += e0 * b2f(v0.y) + e1 * b2f(v1.y);
    az += e0 * b2f(v0.z) + e1 * b2f(v1.z);
    aw += e0 * b2f(v0.w) + e1 * b2f(v1.w);
  }
  if (p < row1) {
    int s = csr_src[p];
    const unsigned short* base = &qkvsb[(size_t)s * 512];
    ushort4 kr = *(const ushort4*)(base + 128 + l * 4);
    ushort4 vr = *(const ushort4*)(base + 256 + l * 4);
    float d = qx * b2f(kr.x) + qy * b2f(kr.y) + qz * b2f(kr.z) + qw * b2f(kr.w);
    d += __shfl_xor(d, 1, 32);
    d += __shfl_xor(d, 2, 32);
    d += __shfl_xor(d, 4, 32);
    float e = __expf(d * 0.17677669529663687f);
    z += e;
    ax += e * b2f(vr.x); ay += e * b2f(vr.y);
    az += e * b2f(vr.z); aw += e * b2f(vr.w);
  }
  const float rz = (z > 0.f) ? (1.f / z) : 0.f;  // guard in-degree-0 nodes
  ushort4 su = *(const ushort4*)&qkvsb[(size_t)node * 512 + 384 + l * 4];
  ushort4 o;
  o.x = f2b(b2f(su.x) + ax * rz);
  o.y = f2b(b2f(su.y) + ay * rz);
  o.z = f2b(b2f(su.z) + az * rz);
  o.w = f2b(b2f(su.w) + aw * rz);
  *(ushort4*)&qkvsb[(size_t)node * 512 + 384 + l * 4] = o;
}

extern "C" void kernel_launch(void* const* d_in, const int* in_sizes, int n_in,
                              void* d_out, int out_size, void* d_ws, size_t ws_size,
                              hipStream_t stream) {
  const float* x   = (const float*)d_in[0];
  const int*   ei  = (const int*)d_in[1];
  const float* Wq  = (const float*)d_in[2];
  const float* bq  = (const float*)d_in[3];
  const float* Wk  = (const float*)d_in[4];
  const float* bk  = (const float*)d_in[5];
  const float* Wv  = (const float*)d_in[6];
  const float* bv  = (const float*)d_in[7];
  const float* Wsk = (const float*)d_in[8];
  const float* bsk = (const float*)d_in[9];
  const float* Wo  = (const float*)d_in[10];
  const float* bo  = (const float*)d_in[11];
  const float* l1w = (const float*)d_in[12];
  const float* l1b = (const float*)d_in[13];
  const float* l2w = (const float*)d_in[14];
  const float* l2b = (const float*)d_in[15];
  const float* W1  = (const float*)d_in[16];
  const float* b1  = (const float*)d_in[17];
  const float* W2  = (const float*)d_in[18];
  const float* b2  = (const float*)d_in[19];

  // ---- workspace layout (~158 MB peak) ----
  unsigned short* wsu = (unsigned short*)d_ws;
  unsigned short* qkvsb = wsu;                           // [N,512] bf16
  unsigned short* out2b = wsu + (size_t)NN * 512;        // [N,128] bf16
  unsigned short* xb    = out2b + (size_t)NN * DD;       // [N,128] bf16
  int* csr_src = (int*)(xb + (size_t)NN * DD);           // NE
  int* rowptr  = csr_src + NE;                           // N+1
  int* cnt     = rowptr + NN + 1;                        // N
  int* part    = cnt + NN;                               // 391
  int* partx   = part + 512;                             // 512
  size_t woff = (size_t)((partx + 512) - (int*)d_ws);
  woff = (woff + 3) & ~(size_t)3;                        // 16B-align weights
  unsigned short* Wqkvs = (unsigned short*)((int*)d_ws + woff);  // [512,128]
  unsigned short* Wob   = Wqkvs + 512 * DD;                      // [128,128]
  unsigned short* W1b   = Wob + DD * DD;                         // [512,128]
  unsigned short* W2b   = W1b + (size_t)HIDD * DD;               // [128,512]
  float* bias512        = (float*)(W2b + (size_t)DD * HIDD);

  float* outf = (float*)d_out;

  const int GX = (NN + 127) / 128;  // 782
  dim3 blk(256);

  // x -> bf16 once; weights/biases cast+pack (one launch)
  k_cast<<<dim3(12500), blk, 0, stream>>>(x, xb, NN * DD);
  k_castw<<<dim3(209), blk, 0, stream>>>(Wq, Wk, Wv, Wsk, Wo, W1, W2, bq, bk, bv, bsk,
                                         Wqkvs, Wob, W1b, W2b, bias512);

  // CSR build
  k_zero_cnt<<<dim3(391), blk, 0, stream>>>(cnt);
  k_count<<<dim3(1954), blk, 0, stream>>>(ei, cnt);
  k_scan1<<<dim3(391), blk, 0, stream>>>(cnt, rowptr, part);
  k_scan2<<<dim3(1), dim3(512), 0, stream>>>(part, partx);
  k_scan3<<<dim3(391), blk, 0, stream>>>(rowptr, partx, cnt);
  k_scatter<<<dim3(1954), blk, 0, stream>>>(ei, cnt, csr_src);

  // fused q|k|v|skip projection: xb -> qkvsb bf16 [N,512] (A read once, cg loop)
  k_gemm_cg<<<dim3(GX), blk, 0, stream>>>(xb, Wqkvs, bias512, qkvsb);

  // single-pass attention (conv lands in skip slot)
  k_attn<<<dim3(12500), blk, 0, stream>>>(csr_src, rowptr, qkvsb);

  // out projection (A = conv slot, lda=512) + residual(xb) + LN1 -> out2b bf16
  k_gemm_ln1<<<dim3(GX), blk, 0, stream>>>(qkvsb + 384, Wob, bo, xb, l1w, l1b, out2b);

  // fused FFN (+ residual out2b + LN2) -> d_out fp32; hid never hits HBM
  k_ffn_fused<<<dim3(GX), blk, 0, stream>>>(out2b, W1b, b1, W2b, b2, l2w, l2b, outf);
}